// Round 1
// 595.480 us; speedup vs baseline: 1.0178x; 1.0178x over previous
//
#include <hip/hip_runtime.h>
#include <hip/hip_bf16.h>
#include <stdint.h>

typedef unsigned short u16;
typedef __attribute__((ext_vector_type(8))) short short8;
typedef __attribute__((ext_vector_type(4))) float f32x4;

__device__ inline u16 f2bf(float f) {
    union { float f; unsigned int u; } x; x.f = f;
    unsigned int u = x.u;
    unsigned int r = (u + 0x7FFFu + ((u >> 16) & 1u)) >> 16;
    return (u16)r;
}

// async global->LDS, 16B per lane; LDS dest must be wave-uniform base (lane*16 implicit)
__device__ inline void gld_lds16(const u16* g, u16* l) {
    auto const* gp = reinterpret_cast<const __attribute__((address_space(1))) unsigned int*>(
        reinterpret_cast<uintptr_t>(g));
    auto* lp = reinterpret_cast<__attribute__((address_space(3))) unsigned int*>(
        reinterpret_cast<uintptr_t>(l));
    __builtin_amdgcn_global_load_lds(gp, lp, 16, 0, 0);
}

// ---------------- prepass: convert x + weights to bf16, 8 elems/thread ----------------
#define NX8 4816896   // 100352*384/8
#define NQ8 55296     // 1152*384/8
#define NP8 18432     // 384*384/8
__global__ __launch_bounds__(256) void prep_all(const float* __restrict__ x,
                                                const float* __restrict__ qw,
                                                const float* __restrict__ pw,
                                                u16* __restrict__ xb,
                                                u16* __restrict__ wq,
                                                u16* __restrict__ wp) {
    size_t i = (size_t)blockIdx.x * 256 + threadIdx.x;
    const float* src; u16* dst; size_t off;
    if (i < NX8)            { src = x;  dst = xb; off = i; }
    else if (i < NX8 + NQ8) { src = qw; dst = wq; off = i - NX8; }
    else                    { src = pw; dst = wp; off = i - (NX8 + NQ8); }
    float4 v0 = ((const float4*)src)[off * 2];
    float4 v1 = ((const float4*)src)[off * 2 + 1];
    u16 h[8];
    h[0] = f2bf(v0.x); h[1] = f2bf(v0.y); h[2] = f2bf(v0.z); h[3] = f2bf(v0.w);
    h[4] = f2bf(v1.x); h[5] = f2bf(v1.y); h[6] = f2bf(v1.z); h[7] = f2bf(v1.w);
    *(uint4*)(dst + off * 8) = *(const uint4*)h;
}

// ---------------- kernel 1: QKV GEMM (bf16 in, global_load_lds staging) ----------------
// C[m,n] = sum_k xb[m,k] * wq[n,k] + b[n]; q part scaled. M=100352, N=1152, K=384.
// Output layout: GEMM-natural [m][1152] (m = b*49+tok, n = s*384 + h*32 + d).
// MFMA operands SWAPPED (mfma(B,A)) so each thread's 4 acc regs = 4 consecutive n
// of one m-row -> packed 8B bf16x4 stores, no div-by-49/384 in the epilogue.
// 1-D grid 7056, XCD-swizzled: xcd = lin&7 owns m-stripes [98*xcd, 98*xcd+97].
__global__ __launch_bounds__(256) void qkv_gemm(const u16* __restrict__ xb,
                                                const u16* __restrict__ wq,
                                                const float* __restrict__ bias,
                                                u16* __restrict__ qkv_out) {
    __shared__ u16 As[128 * 32];
    __shared__ u16 Bs[128 * 32];
    const int tid = threadIdx.x;
    const int wave = tid >> 6, lane = tid & 63;
    const int lr = lane >> 4, lc = lane & 15;
    const int wm = (wave & 1) * 64, wn = (wave >> 1) * 64;
    const int lin = blockIdx.x;
    const int xcd = lin & 7;
    const int idx = lin >> 3;            // 0..881
    const int nBase = (idx % 9) * 128;
    const int mBase = (xcd * 98 + idx / 9) * 128;

    f32x4 acc[4][4] = {};

    const int srow = lane >> 2, scol = (lane & 3) * 8;
    const u16* aSrc = xb + (size_t)(mBase + wave * 32 + srow) * 384 + scol;
    const u16* bSrc = wq + (size_t)(nBase + wave * 32 + srow) * 384 + scol;
    u16* aDst = &As[wave * 1024];
    u16* bDst = &Bs[wave * 1024];

    for (int k0 = 0; k0 < 384; k0 += 32) {
        gld_lds16(aSrc + k0, aDst);
        gld_lds16(aSrc + k0 + (size_t)16 * 384, aDst + 512);
        gld_lds16(bSrc + k0, bDst);
        gld_lds16(bSrc + k0 + (size_t)16 * 384, bDst + 512);
        __syncthreads();
        short8 af[4], bfr[4];
#pragma unroll
        for (int i = 0; i < 4; ++i)
            af[i] = *(const short8*)&As[(wm + i * 16 + lc) * 32 + lr * 8];
#pragma unroll
        for (int j = 0; j < 4; ++j)
            bfr[j] = *(const short8*)&Bs[(wn + j * 16 + lc) * 32 + lr * 8];
#pragma unroll
        for (int i = 0; i < 4; ++i)
#pragma unroll
            for (int j = 0; j < 4; ++j)
                acc[i][j] = __builtin_amdgcn_mfma_f32_16x16x32_bf16(bfr[j], af[i], acc[i][j], 0, 0, 0);
        __syncthreads();
    }

    // epilogue: swapped-C mapping: m = wm+i*16+lc (lane), n = wn+j*16+lr*4+r (reg)
    const float scale = 0.17677669529663687f;  // 32^-0.5
#pragma unroll
    for (int j = 0; j < 4; ++j) {
        int gnb = nBase + wn + j * 16 + lr * 4;
        float4 bv = *(const float4*)&bias[gnb];
        float mult = (gnb < 384) ? scale : 1.0f;   // q-section; group of 4 never straddles
#pragma unroll
        for (int i = 0; i < 4; ++i) {
            int gm = mBase + wm + i * 16 + lc;
            union { u16 h[4]; uint2 u; } pk;
            pk.h[0] = f2bf((acc[i][j][0] + bv.x) * mult);
            pk.h[1] = f2bf((acc[i][j][1] + bv.y) * mult);
            pk.h[2] = f2bf((acc[i][j][2] + bv.z) * mult);
            pk.h[3] = f2bf((acc[i][j][3] + bv.w) * mult);
            *(uint2*)(qkv_out + (size_t)gm * 1152 + gnb) = pk.u;
        }
    }
}

// ---------------- kernel 2: windowed attention ----------------
// one wave per (b,h); 4 waves/block; LDS 52.2 KB -> 3 blocks/CU; mask read from L2.
// qkv layout: [b*49+tok][1152], n = s*384 + h*32 + d.
#define PST 68  // P/Vt LDS row stride (bf16 elems)
__global__ __launch_bounds__(256, 3) void attn_kernel(const u16* __restrict__ qkv,
                                                      const float* __restrict__ mask,
                                                      u16* __restrict__ aout) {
    __shared__ u16 P_s[4][64 * PST];
    __shared__ u16 Vt_s[4][32 * PST];
    const int tid = threadIdx.x;
    const int wave = tid >> 6, lane = tid & 63;
    const int lr = lane >> 4, lc = lane & 15;
    const int bid = blockIdx.x;
    const int b = bid / 3;
    const int h = (bid - b * 3) * 4 + wave;
    const int w = b & 63;
    const float* mrow = mask + (size_t)w * 2401;

    const u16* Q = qkv + (size_t)b * 49 * 1152 + h * 32;
    const u16* K = Q + 384;
    const u16* V = Q + 768;

    // stage V transposed: Vt[d][j], zero-padded j>=49
    {
        u16 vv[32];
        if (lane < 49) {
#pragma unroll
            for (int c = 0; c < 4; ++c)
                *(uint4*)&vv[c * 8] = *(const uint4*)(V + (size_t)lane * 1152 + c * 8);
        } else {
#pragma unroll
            for (int c = 0; c < 32; ++c) vv[c] = 0;
        }
#pragma unroll
        for (int d = 0; d < 32; ++d)
            Vt_s[wave][d * PST + lane] = vv[d];
    }

    // Q/K fragments straight from global (16B contiguous per lane, row stride 1152)
    short8 qf[4], kf[4];
    const short8 z8 = {0, 0, 0, 0, 0, 0, 0, 0};
#pragma unroll
    for (int i = 0; i < 4; ++i) {
        int row = i * 16 + lc;
        qf[i] = (row < 49) ? *(const short8*)(Q + (size_t)row * 1152 + lr * 8) : z8;
        kf[i] = (row < 49) ? *(const short8*)(K + (size_t)row * 1152 + lr * 8) : z8;
    }
    __syncthreads();

    // S = Q K^T  (64x64 padded, 16 MFMA)
    f32x4 S[4][4] = {};
#pragma unroll
    for (int i = 0; i < 4; ++i)
#pragma unroll
        for (int j = 0; j < 4; ++j)
            S[i][j] = __builtin_amdgcn_mfma_f32_16x16x32_bf16(qf[i], kf[j], S[i][j], 0, 0, 0);

    // softmax per row, no max-subtraction (logits bounded ~±8; fp32 exp safe).
    // row i lives on 16 lanes (lc) x 4 sj, fixed reg r.
    float l_sum[4][4];
#pragma unroll
    for (int si = 0; si < 4; ++si) {
#pragma unroll
        for (int r = 0; r < 4; ++r) {
            int i = si * 16 + lr * 4 + r;
            int im = (i < 49) ? i : 48;  // clamp for padded rows (never stored)
            float s = 0.0f;
#pragma unroll
            for (int sj = 0; sj < 4; ++sj) {
                int jc = sj * 16 + lc;
                float t = (jc < 49) ? (S[si][sj][r] + mrow[im * 49 + jc]) : -1e30f;
                float p = __expf(t);
                s += p;
                S[si][sj][r] = p;
            }
            s += __shfl_xor(s, 1);
            s += __shfl_xor(s, 2);
            s += __shfl_xor(s, 4);
            s += __shfl_xor(s, 8);
            l_sum[si][r] = s;
        }
    }

    // P -> LDS (bf16) to re-layout C-frag -> A-frag
#pragma unroll
    for (int si = 0; si < 4; ++si)
#pragma unroll
        for (int sj = 0; sj < 4; ++sj)
#pragma unroll
            for (int r = 0; r < 4; ++r) {
                int i = si * 16 + lr * 4 + r;
                int jc = sj * 16 + lc;
                P_s[wave][i * PST + jc] = f2bf(S[si][sj][r]);
            }
    __syncthreads();

    // O = P V  (64x32, K=64 -> 16 MFMA)
    short8 vf[2][2];
#pragma unroll
    for (int nt = 0; nt < 2; ++nt)
#pragma unroll
        for (int kt = 0; kt < 2; ++kt)
            vf[nt][kt] = *(const short8*)&Vt_s[wave][(nt * 16 + lc) * PST + kt * 32 + lr * 8];

    f32x4 O[4][2] = {};
#pragma unroll
    for (int si = 0; si < 4; ++si) {
#pragma unroll
        for (int kt = 0; kt < 2; ++kt) {
            short8 pf = *(const short8*)&P_s[wave][(si * 16 + lc) * PST + kt * 32 + lr * 8];
#pragma unroll
            for (int nt = 0; nt < 2; ++nt)
                O[si][nt] = __builtin_amdgcn_mfma_f32_16x16x32_bf16(pf, vf[nt][kt], O[si][nt], 0, 0, 0);
        }
    }

    // epilogue: divide by row sum, store bf16 to [b*49+i][h*32+d]
#pragma unroll
    for (int si = 0; si < 4; ++si) {
#pragma unroll
        for (int nt = 0; nt < 2; ++nt) {
#pragma unroll
            for (int r = 0; r < 4; ++r) {
                int i = si * 16 + lr * 4 + r;
                if (i < 49) {
                    float val = O[si][nt][r] * __builtin_amdgcn_rcpf(l_sum[si][r]);
                    aout[(size_t)(b * 49 + i) * 384 + h * 32 + nt * 16 + lc] = f2bf(val);
                }
            }
        }
    }
}

// ---------------- kernel 3: proj GEMM (global_load_lds staging, XCD swizzle) ----------------
// out[m,n] = sum_k a[m,k] * wp[n,k] + b[n]; fp32 out. M=100352, N=384, K=384.
// MFMA operands swapped -> 4 consecutive n per thread -> dwordx4 stores.
__global__ __launch_bounds__(256) void proj_gemm(const u16* __restrict__ a,
                                                 const u16* __restrict__ wp,
                                                 const float* __restrict__ bias,
                                                 float* __restrict__ out) {
    __shared__ u16 As[128 * 32];
    __shared__ u16 Bs[128 * 32];
    const int tid = threadIdx.x;
    const int wave = tid >> 6, lane = tid & 63;
    const int lr = lane >> 4, lc = lane & 15;
    const int wm = (wave & 1) * 64, wn = (wave >> 1) * 64;
    const int lin = blockIdx.x;
    const int xcd = lin & 7;
    const int idx = lin >> 3;            // 0..293
    const int nBase = (idx % 3) * 128;
    const int mBase = (xcd * 98 + idx / 3) * 128;

    f32x4 acc[4][4] = {};

    const int srow = lane >> 2, scol = (lane & 3) * 8;
    const u16* aSrc = a  + (size_t)(mBase + wave * 32 + srow) * 384 + scol;
    const u16* bSrc = wp + (size_t)(nBase + wave * 32 + srow) * 384 + scol;
    u16* aDst = &As[wave * 1024];
    u16* bDst = &Bs[wave * 1024];

    for (int k0 = 0; k0 < 384; k0 += 32) {
        gld_lds16(aSrc + k0, aDst);
        gld_lds16(aSrc + k0 + (size_t)16 * 384, aDst + 512);
        gld_lds16(bSrc + k0, bDst);
        gld_lds16(bSrc + k0 + (size_t)16 * 384, bDst + 512);
        __syncthreads();
        short8 af[4], bfr[4];
#pragma unroll
        for (int i = 0; i < 4; ++i)
            af[i] = *(const short8*)&As[(wm + i * 16 + lc) * 32 + lr * 8];
#pragma unroll
        for (int j = 0; j < 4; ++j)
            bfr[j] = *(const short8*)&Bs[(wn + j * 16 + lc) * 32 + lr * 8];
#pragma unroll
        for (int i = 0; i < 4; ++i)
#pragma unroll
            for (int j = 0; j < 4; ++j)
                acc[i][j] = __builtin_amdgcn_mfma_f32_16x16x32_bf16(bfr[j], af[i], acc[i][j], 0, 0, 0);
        __syncthreads();
    }

    // epilogue: swapped-C mapping: m = wm+i*16+lc (lane), n = wn+j*16+lr*4+r (reg)
#pragma unroll
    for (int j = 0; j < 4; ++j) {
        int gnb = nBase + wn + j * 16 + lr * 4;
        float4 bv = *(const float4*)&bias[gnb];
#pragma unroll
        for (int i = 0; i < 4; ++i) {
            int gm = mBase + wm + i * 16 + lc;
            float4 o;
            o.x = acc[i][j][0] + bv.x;
            o.y = acc[i][j][1] + bv.y;
            o.z = acc[i][j][2] + bv.z;
            o.w = acc[i][j][3] + bv.w;
            *(float4*)(out + (size_t)gm * 384 + gnb) = o;
        }
    }
}

// ---------------- launch ----------------
extern "C" void kernel_launch(void* const* d_in, const int* in_sizes, int n_in,
                              void* d_out, int out_size, void* d_ws, size_t ws_size,
                              hipStream_t stream) {
    const float* x      = (const float*)d_in[0];
    const float* mask   = (const float*)d_in[1];
    const float* qkv_w  = (const float*)d_in[2];
    const float* qkv_b  = (const float*)d_in[3];
    const float* proj_w = (const float*)d_in[4];
    const float* proj_b = (const float*)d_in[5];
    float* out = (float*)d_out;

    char* ws = (char*)d_ws;
    u16* wq   = (u16*)ws;                                   // 1152*384*2   = 884736 B
    u16* wp   = (u16*)(ws + 884736);                        // 384*384*2    = 294912 B
    u16* qkvb = (u16*)(ws + 884736 + 294912);               // 231211008 B
    // xb aliases the attn-out buffer: xb is dead before attn_kernel writes it
    u16* xb   = (u16*)(ws + 884736 + 294912 + 231211008);   // 77070336 B
    u16* attn = xb;

    prep_all<<<19104, 256, 0, stream>>>(x, qkv_w, proj_w, xb, wq, wp);
    qkv_gemm<<<7056, 256, 0, stream>>>(xb, wq, qkv_b, qkvb);
    attn_kernel<<<6144, 256, 0, stream>>>(qkvb, mask, attn);
    proj_gemm<<<2352, 256, 0, stream>>>(attn, wp, proj_b, out);
}

// Round 3
// 570.086 us; speedup vs baseline: 1.0631x; 1.0445x over previous
//
#include <hip/hip_runtime.h>
#include <hip/hip_bf16.h>
#include <stdint.h>

typedef unsigned short u16;
typedef __attribute__((ext_vector_type(8))) short short8;
typedef __attribute__((ext_vector_type(4))) short s4v;
typedef __attribute__((ext_vector_type(4))) float f32x4;

__device__ inline u16 f2bf(float f) {
    union { float f; unsigned int u; } x; x.f = f;
    unsigned int u = x.u;
    unsigned int r = (u + 0x7FFFu + ((u >> 16) & 1u)) >> 16;
    return (u16)r;
}

// async global->LDS, 16B per lane; LDS dest must be wave-uniform base (lane*16 implicit)
__device__ inline void gld_lds16(const u16* g, u16* l) {
    auto const* gp = reinterpret_cast<const __attribute__((address_space(1))) unsigned int*>(
        reinterpret_cast<uintptr_t>(g));
    auto* lp = reinterpret_cast<__attribute__((address_space(3))) unsigned int*>(
        reinterpret_cast<uintptr_t>(l));
    __builtin_amdgcn_global_load_lds(gp, lp, 16, 0, 0);
}

// 16x16x16 bf16 MFMA: prefer intrinsics (compiler-managed hazards); asm fallback carries
// explicit s_nop fences (VALU->MFMA src: 2 states; MFMA D -> VALU read: 16 states).
#if __has_builtin(__builtin_amdgcn_mfma_f32_16x16x16bf16_1k)
#define MFMA16(a, b, c) __builtin_amdgcn_mfma_f32_16x16x16bf16_1k((a), (b), (c), 0, 0, 0)
#elif __has_builtin(__builtin_amdgcn_mfma_f32_16x16x16_bf16)
#define MFMA16(a, b, c) __builtin_amdgcn_mfma_f32_16x16x16_bf16((a), (b), (c), 0, 0, 0)
#else
__device__ inline f32x4 mfma16_asm(s4v a, s4v b, f32x4 c) {
    asm volatile("s_nop 1\n\tv_mfma_f32_16x16x16_bf16 %0, %1, %2, %0\n\ts_nop 7\n\ts_nop 7"
                 : "+v"(c) : "v"(a), "v"(b));
    return c;
}
#define MFMA16(a, b, c) mfma16_asm((a), (b), (c))
#endif

// ---------------- prepass: convert x + weights to bf16, 8 elems/thread ----------------
#define NX8 4816896   // 100352*384/8
#define NQ8 55296     // 1152*384/8
#define NP8 18432     // 384*384/8
__global__ __launch_bounds__(256) void prep_all(const float* __restrict__ x,
                                                const float* __restrict__ qw,
                                                const float* __restrict__ pw,
                                                u16* __restrict__ xb,
                                                u16* __restrict__ wq,
                                                u16* __restrict__ wp) {
    size_t i = (size_t)blockIdx.x * 256 + threadIdx.x;
    const float* src; u16* dst; size_t off;
    if (i < NX8)            { src = x;  dst = xb; off = i; }
    else if (i < NX8 + NQ8) { src = qw; dst = wq; off = i - NX8; }
    else                    { src = pw; dst = wp; off = i - (NX8 + NQ8); }
    float4 v0 = ((const float4*)src)[off * 2];
    float4 v1 = ((const float4*)src)[off * 2 + 1];
    u16 h[8];
    h[0] = f2bf(v0.x); h[1] = f2bf(v0.y); h[2] = f2bf(v0.z); h[3] = f2bf(v0.w);
    h[4] = f2bf(v1.x); h[5] = f2bf(v1.y); h[6] = f2bf(v1.z); h[7] = f2bf(v1.w);
    *(uint4*)(dst + off * 8) = *(const uint4*)h;
}

// ---------------- kernel 1: QKV GEMM (verified round-1 version) ----------------
__global__ __launch_bounds__(256) void qkv_gemm(const u16* __restrict__ xb,
                                                const u16* __restrict__ wq,
                                                const float* __restrict__ bias,
                                                u16* __restrict__ qkv_out) {
    __shared__ u16 As[128 * 32];
    __shared__ u16 Bs[128 * 32];
    const int tid = threadIdx.x;
    const int wave = tid >> 6, lane = tid & 63;
    const int lr = lane >> 4, lc = lane & 15;
    const int wm = (wave & 1) * 64, wn = (wave >> 1) * 64;
    const int lin = blockIdx.x;
    const int xcd = lin & 7;
    const int idx = lin >> 3;            // 0..881
    const int nBase = (idx % 9) * 128;
    const int mBase = (xcd * 98 + idx / 9) * 128;

    f32x4 acc[4][4] = {};

    const int srow = lane >> 2, scol = (lane & 3) * 8;
    const u16* aSrc = xb + (size_t)(mBase + wave * 32 + srow) * 384 + scol;
    const u16* bSrc = wq + (size_t)(nBase + wave * 32 + srow) * 384 + scol;
    u16* aDst = &As[wave * 1024];
    u16* bDst = &Bs[wave * 1024];

    for (int k0 = 0; k0 < 384; k0 += 32) {
        gld_lds16(aSrc + k0, aDst);
        gld_lds16(aSrc + k0 + (size_t)16 * 384, aDst + 512);
        gld_lds16(bSrc + k0, bDst);
        gld_lds16(bSrc + k0 + (size_t)16 * 384, bDst + 512);
        __syncthreads();
        short8 af[4], bfr[4];
#pragma unroll
        for (int i = 0; i < 4; ++i)
            af[i] = *(const short8*)&As[(wm + i * 16 + lc) * 32 + lr * 8];
#pragma unroll
        for (int j = 0; j < 4; ++j)
            bfr[j] = *(const short8*)&Bs[(wn + j * 16 + lc) * 32 + lr * 8];
#pragma unroll
        for (int i = 0; i < 4; ++i)
#pragma unroll
            for (int j = 0; j < 4; ++j)
                acc[i][j] = __builtin_amdgcn_mfma_f32_16x16x32_bf16(bfr[j], af[i], acc[i][j], 0, 0, 0);
        __syncthreads();
    }

    // epilogue: swapped-C mapping: m = wm+i*16+lc (lane), n = wn+j*16+lr*4+r (reg)
    const float scale = 0.17677669529663687f;  // 32^-0.5
#pragma unroll
    for (int j = 0; j < 4; ++j) {
        int gnb = nBase + wn + j * 16 + lr * 4;
        float4 bv = *(const float4*)&bias[gnb];
        float mult = (gnb < 384) ? scale : 1.0f;   // q-section; group of 4 never straddles
#pragma unroll
        for (int i = 0; i < 4; ++i) {
            int gm = mBase + wm + i * 16 + lc;
            union { u16 h[4]; uint2 u; } pk;
            pk.h[0] = f2bf((acc[i][j][0] + bv.x) * mult);
            pk.h[1] = f2bf((acc[i][j][1] + bv.y) * mult);
            pk.h[2] = f2bf((acc[i][j][2] + bv.z) * mult);
            pk.h[3] = f2bf((acc[i][j][3] + bv.w) * mult);
            *(uint2*)(qkv_out + (size_t)gm * 1152 + gnb) = pk.u;
        }
    }
}

// ---------------- kernel 2: windowed attention (swapped-QK^T, in-register softmax) ----
// one wave per (b,h); 4 waves/block; LDS 17.4 KB (Vt only); one barrier.
// qkv layout: [b*49+tok][1152], n = s*384 + h*32 + d.
// S2 = mfma(K,Q): thread (lr,lc) reg r of tile (si,sj) holds S[k=sj*16+lr*4+r][q=si*16+lc]
//   (A-frag m=lc / B-frag n=lc / C row=lr*4+r,col=lc -- all HW-verified in rounds 0/1).
// -> k-reduce = in-reg adds + shfl_xor(16,32); P regs are exactly the B-frag of the
//    16x16x16 MFMA (4 contiguous k per lane at lr*4), so PV runs straight from registers.
__global__ __launch_bounds__(256, 3) void attn_kernel(const u16* __restrict__ qkv,
                                                      const float* __restrict__ mask,
                                                      u16* __restrict__ aout) {
#define PST 68  // Vt LDS row stride (bf16 elems)
    __shared__ u16 Vt_s[4][32 * PST];
    const int tid = threadIdx.x;
    const int wave = tid >> 6, lane = tid & 63;
    const int lr = lane >> 4, lc = lane & 15;
    const int bid = blockIdx.x;
    const int b = bid / 3;
    const int h = (bid - b * 3) * 4 + wave;
    const int w = b & 63;
    const float* mrow = mask + (size_t)w * 2401;

    const u16* Q = qkv + (size_t)b * 49 * 1152 + h * 32;
    const u16* K = Q + 384;
    const u16* V = Q + 768;

    // stage V transposed: Vt[d][j], zero-padded j>=49
    {
        u16 vv[32];
        if (lane < 49) {
#pragma unroll
            for (int c = 0; c < 4; ++c)
                *(uint4*)&vv[c * 8] = *(const uint4*)(V + (size_t)lane * 1152 + c * 8);
        } else {
#pragma unroll
            for (int c = 0; c < 32; ++c) vv[c] = 0;
        }
#pragma unroll
        for (int d = 0; d < 32; ++d)
            Vt_s[wave][d * PST + lane] = vv[d];
    }

    // Q/K fragments straight from global (16B contiguous per lane, row stride 1152)
    short8 qf[4], kf[4];
    const short8 z8 = {0, 0, 0, 0, 0, 0, 0, 0};
#pragma unroll
    for (int i = 0; i < 4; ++i) {
        int row = i * 16 + lc;
        qf[i] = (row < 49) ? *(const short8*)(Q + (size_t)row * 1152 + lr * 8) : z8;
        kf[i] = (row < 49) ? *(const short8*)(K + (size_t)row * 1152 + lr * 8) : z8;
    }

    __syncthreads();   // Vt_s writes -> vfA reads

    // Vt A-frags for 16x16x16: lane (lr,lc) holds Vt[d=nt*16+lc][k=sj*16+lr*4 .. +3]
    s4v vfA[2][4];
#pragma unroll
    for (int nt = 0; nt < 2; ++nt)
#pragma unroll
        for (int sj = 0; sj < 4; ++sj)
            vfA[nt][sj] = *(const s4v*)&Vt_s[wave][(nt * 16 + lc) * PST + sj * 16 + lr * 4];

    // S2 = K Q^T (swapped): tile (si,sj): rows k (reg), cols q (lane)
    f32x4 S2[4][4] = {};
#pragma unroll
    for (int si = 0; si < 4; ++si)
#pragma unroll
        for (int sj = 0; sj < 4; ++sj)
            S2[si][sj] = __builtin_amdgcn_mfma_f32_16x16x32_bf16(kf[sj], qf[si], S2[si][sj], 0, 0, 0);

    // per-q-tile: softmax (in-register) -> P-frag pack -> PV -> store
    const size_t orow = (size_t)b * 49 * 384 + h * 32 + lr * 4;
#pragma unroll
    for (int si = 0; si < 4; ++si) {
        int q = si * 16 + lc;
        int im = (q < 49) ? q : 48;       // clamped; padded q never stored
        const float* mq = mrow + im * 49;
        float s = 0.0f;
        s4v pfq[4];
#pragma unroll
        for (int sj = 0; sj < 4; ++sj) {
            int kbase = sj * 16 + lr * 4;
            s4v pk;
#pragma unroll
            for (int r = 0; r < 4; ++r) {
                int k = kbase + r;
                float t = (k < 49) ? (S2[si][sj][r] + mq[k]) : -1e30f;
                float p = __expf(t);      // exp(-1e30) = 0: padded k contributes nothing
                s += p;
                pk[r] = (short)f2bf(p);
            }
            pfq[sj] = pk;
        }
        // complete k-sum: other k-chunks live on lanes differing in lr (bits 4,5)
        s += __shfl_xor(s, 16);
        s += __shfl_xor(s, 32);

        f32x4 O0 = {}, O1 = {};
#pragma unroll
        for (int sj = 0; sj < 4; ++sj) {
            O0 = MFMA16(vfA[0][sj], pfq[sj], O0);
            O1 = MFMA16(vfA[1][sj], pfq[sj], O1);
        }

        if (q < 49) {
            float rl = __builtin_amdgcn_rcpf(s);
            union { u16 h[4]; uint2 u; } pk;
            pk.h[0] = f2bf(O0[0] * rl); pk.h[1] = f2bf(O0[1] * rl);
            pk.h[2] = f2bf(O0[2] * rl); pk.h[3] = f2bf(O0[3] * rl);
            *(uint2*)(aout + orow + (size_t)q * 384) = pk.u;
            pk.h[0] = f2bf(O1[0] * rl); pk.h[1] = f2bf(O1[1] * rl);
            pk.h[2] = f2bf(O1[2] * rl); pk.h[3] = f2bf(O1[3] * rl);
            *(uint2*)(aout + orow + (size_t)q * 384 + 16) = pk.u;
        }
    }
#undef PST
}

// ---------------- kernel 3: proj GEMM (verified round-1 version) ----------------
__global__ __launch_bounds__(256) void proj_gemm(const u16* __restrict__ a,
                                                 const u16* __restrict__ wp,
                                                 const float* __restrict__ bias,
                                                 float* __restrict__ out) {
    __shared__ u16 As[128 * 32];
    __shared__ u16 Bs[128 * 32];
    const int tid = threadIdx.x;
    const int wave = tid >> 6, lane = tid & 63;
    const int lr = lane >> 4, lc = lane & 15;
    const int wm = (wave & 1) * 64, wn = (wave >> 1) * 64;
    const int lin = blockIdx.x;
    const int xcd = lin & 7;
    const int idx = lin >> 3;            // 0..293
    const int nBase = (idx % 3) * 128;
    const int mBase = (xcd * 98 + idx / 3) * 128;

    f32x4 acc[4][4] = {};

    const int srow = lane >> 2, scol = (lane & 3) * 8;
    const u16* aSrc = a  + (size_t)(mBase + wave * 32 + srow) * 384 + scol;
    const u16* bSrc = wp + (size_t)(nBase + wave * 32 + srow) * 384 + scol;
    u16* aDst = &As[wave * 1024];
    u16* bDst = &Bs[wave * 1024];

    for (int k0 = 0; k0 < 384; k0 += 32) {
        gld_lds16(aSrc + k0, aDst);
        gld_lds16(aSrc + k0 + (size_t)16 * 384, aDst + 512);
        gld_lds16(bSrc + k0, bDst);
        gld_lds16(bSrc + k0 + (size_t)16 * 384, bDst + 512);
        __syncthreads();
        short8 af[4], bfr[4];
#pragma unroll
        for (int i = 0; i < 4; ++i)
            af[i] = *(const short8*)&As[(wm + i * 16 + lc) * 32 + lr * 8];
#pragma unroll
        for (int j = 0; j < 4; ++j)
            bfr[j] = *(const short8*)&Bs[(wn + j * 16 + lc) * 32 + lr * 8];
#pragma unroll
        for (int i = 0; i < 4; ++i)
#pragma unroll
            for (int j = 0; j < 4; ++j)
                acc[i][j] = __builtin_amdgcn_mfma_f32_16x16x32_bf16(bfr[j], af[i], acc[i][j], 0, 0, 0);
        __syncthreads();
    }

    // epilogue: swapped-C mapping: m = wm+i*16+lc (lane), n = wn+j*16+lr*4+r (reg)
#pragma unroll
    for (int j = 0; j < 4; ++j) {
        int gnb = nBase + wn + j * 16 + lr * 4;
        float4 bv = *(const float4*)&bias[gnb];
#pragma unroll
        for (int i = 0; i < 4; ++i) {
            int gm = mBase + wm + i * 16 + lc;
            float4 o;
            o.x = acc[i][j][0] + bv.x;
            o.y = acc[i][j][1] + bv.y;
            o.z = acc[i][j][2] + bv.z;
            o.w = acc[i][j][3] + bv.w;
            *(float4*)(out + (size_t)gm * 384 + gnb) = o;
        }
    }
}

// ---------------- launch ----------------
extern "C" void kernel_launch(void* const* d_in, const int* in_sizes, int n_in,
                              void* d_out, int out_size, void* d_ws, size_t ws_size,
                              hipStream_t stream) {
    const float* x      = (const float*)d_in[0];
    const float* mask   = (const float*)d_in[1];
    const float* qkv_w  = (const float*)d_in[2];
    const float* qkv_b  = (const float*)d_in[3];
    const float* proj_w = (const float*)d_in[4];
    const float* proj_b = (const float*)d_in[5];
    float* out = (float*)d_out;

    char* ws = (char*)d_ws;
    u16* wq   = (u16*)ws;                                   // 1152*384*2   = 884736 B
    u16* wp   = (u16*)(ws + 884736);                        // 384*384*2    = 294912 B
    u16* qkvb = (u16*)(ws + 1179648);                       // 231211008 B
    // xb aliases the attn-out buffer: xb is dead before attn_kernel writes it
    u16* xb   = (u16*)(ws + 232390656);                     // 77070336 B
    u16* attn = xb;

    prep_all<<<19104, 256, 0, stream>>>(x, qkv_w, proj_w, xb, wq, wp);
    qkv_gemm<<<7056, 256, 0, stream>>>(xb, wq, qkv_b, qkvb);
    attn_kernel<<<6144, 256, 0, stream>>>(qkvb, mask, attn);
    proj_gemm<<<2352, 256, 0, stream>>>(attn, wp, proj_b, out);
}

// Round 4
// 561.136 us; speedup vs baseline: 1.0801x; 1.0160x over previous
//
#include <hip/hip_runtime.h>
#include <hip/hip_bf16.h>
#include <stdint.h>

typedef unsigned short u16;
typedef __attribute__((ext_vector_type(8))) short short8;
typedef __attribute__((ext_vector_type(4))) short s4v;
typedef __attribute__((ext_vector_type(4))) float f32x4;

__device__ inline u16 f2bf(float f) {
    union { float f; unsigned int u; } x; x.f = f;
    unsigned int u = x.u;
    unsigned int r = (u + 0x7FFFu + ((u >> 16) & 1u)) >> 16;
    return (u16)r;
}

// async global->LDS, 16B per lane; LDS dest must be wave-uniform base (lane*16 implicit)
__device__ inline void gld_lds16(const u16* g, u16* l) {
    auto const* gp = reinterpret_cast<const __attribute__((address_space(1))) unsigned int*>(
        reinterpret_cast<uintptr_t>(g));
    auto* lp = reinterpret_cast<__attribute__((address_space(3))) unsigned int*>(
        reinterpret_cast<uintptr_t>(l));
    __builtin_amdgcn_global_load_lds(gp, lp, 16, 0, 0);
}

// 16x16x16 bf16 MFMA: prefer intrinsics (compiler-managed hazards); asm fallback carries
// explicit s_nop fences.
#if __has_builtin(__builtin_amdgcn_mfma_f32_16x16x16bf16_1k)
#define MFMA16(a, b, c) __builtin_amdgcn_mfma_f32_16x16x16bf16_1k((a), (b), (c), 0, 0, 0)
#elif __has_builtin(__builtin_amdgcn_mfma_f32_16x16x16_bf16)
#define MFMA16(a, b, c) __builtin_amdgcn_mfma_f32_16x16x16_bf16((a), (b), (c), 0, 0, 0)
#else
__device__ inline f32x4 mfma16_asm(s4v a, s4v b, f32x4 c) {
    asm volatile("s_nop 1\n\tv_mfma_f32_16x16x16_bf16 %0, %1, %2, %0\n\ts_nop 7\n\ts_nop 7"
                 : "+v"(c) : "v"(a), "v"(b));
    return c;
}
#define MFMA16(a, b, c) mfma16_asm((a), (b), (c))
#endif

// ---------------- prepass: convert x + weights to bf16, 8 elems/thread ----------------
#define NX8 4816896   // 100352*384/8
#define NQ8 55296     // 1152*384/8
#define NP8 18432     // 384*384/8
__global__ __launch_bounds__(256) void prep_all(const float* __restrict__ x,
                                                const float* __restrict__ qw,
                                                const float* __restrict__ pw,
                                                u16* __restrict__ xb,
                                                u16* __restrict__ wq,
                                                u16* __restrict__ wp) {
    size_t i = (size_t)blockIdx.x * 256 + threadIdx.x;
    const float* src; u16* dst; size_t off;
    if (i < NX8)            { src = x;  dst = xb; off = i; }
    else if (i < NX8 + NQ8) { src = qw; dst = wq; off = i - NX8; }
    else                    { src = pw; dst = wp; off = i - (NX8 + NQ8); }
    float4 v0 = ((const float4*)src)[off * 2];
    float4 v1 = ((const float4*)src)[off * 2 + 1];
    u16 h[8];
    h[0] = f2bf(v0.x); h[1] = f2bf(v0.y); h[2] = f2bf(v0.z); h[3] = f2bf(v0.w);
    h[4] = f2bf(v1.x); h[5] = f2bf(v1.y); h[6] = f2bf(v1.z); h[7] = f2bf(v1.w);
    *(uint4*)(dst + off * 8) = *(const uint4*)h;
}

// ---------------- kernel 1: QKV GEMM (2-phase double-buffered prefetch) ----------------
// C[m,n] = sum_k xb[m,k] * wq[n,k] + b[n]; M=100352, N=1152, K=384, BK=32, 12 K-steps.
// T3 minimum 2-phase: STAGE(t+1) issued BEFORE compute(t); ONE barrier per K-step.
// Buffer parity: iter t writes buf[(t+1)&1], last read in iter t-1 and released by that
// iter's barrier -> safe. The barrier's vmcnt(0) drain lands after ~300cyc of
// ds_read+MFMA have covered the load latency (vs fully exposed in the 1-phase loop).
__global__ __launch_bounds__(256) void qkv_gemm(const u16* __restrict__ xb,
                                                const u16* __restrict__ wq,
                                                const float* __restrict__ bias,
                                                u16* __restrict__ qkv_out) {
    __shared__ u16 As[2][128 * 32];
    __shared__ u16 Bs[2][128 * 32];
    const int tid = threadIdx.x;
    const int wave = tid >> 6, lane = tid & 63;
    const int lr = lane >> 4, lc = lane & 15;
    const int wm = (wave & 1) * 64, wn = (wave >> 1) * 64;
    const int lin = blockIdx.x;
    const int xcd = lin & 7;
    const int idx = lin >> 3;            // 0..881
    const int nBase = (idx % 9) * 128;
    const int mBase = (xcd * 98 + idx / 9) * 128;

    f32x4 acc[4][4] = {};

    const int srow = lane >> 2, scol = (lane & 3) * 8;
    const u16* aSrc = xb + (size_t)(mBase + wave * 32 + srow) * 384 + scol;
    const u16* bSrc = wq + (size_t)(nBase + wave * 32 + srow) * 384 + scol;

    auto stage = [&](int k0, int buf) {
        u16* aDst = &As[buf][wave * 1024];
        u16* bDst = &Bs[buf][wave * 1024];
        gld_lds16(aSrc + k0, aDst);
        gld_lds16(aSrc + k0 + (size_t)16 * 384, aDst + 512);
        gld_lds16(bSrc + k0, bDst);
        gld_lds16(bSrc + k0 + (size_t)16 * 384, bDst + 512);
    };
    auto compute = [&](int buf) {
        short8 af[4], bfr[4];
#pragma unroll
        for (int i = 0; i < 4; ++i)
            af[i] = *(const short8*)&As[buf][(wm + i * 16 + lc) * 32 + lr * 8];
#pragma unroll
        for (int j = 0; j < 4; ++j)
            bfr[j] = *(const short8*)&Bs[buf][(wn + j * 16 + lc) * 32 + lr * 8];
#pragma unroll
        for (int i = 0; i < 4; ++i)
#pragma unroll
            for (int j = 0; j < 4; ++j)
                acc[i][j] = __builtin_amdgcn_mfma_f32_16x16x32_bf16(bfr[j], af[i], acc[i][j], 0, 0, 0);
    };

    stage(0, 0);
    __syncthreads();
#pragma unroll
    for (int t = 0; t < 11; ++t) {
        stage((t + 1) * 32, (t + 1) & 1);   // issue next-tile loads FIRST
        compute(t & 1);                     // overlap: ds_read+MFMA cover load latency
        __syncthreads();                    // one vmcnt-drain per K-step
    }
    compute(11 & 1);

    // epilogue: swapped-C mapping: m = wm+i*16+lc (lane), n = wn+j*16+lr*4+r (reg)
    const float scale = 0.17677669529663687f;  // 32^-0.5
#pragma unroll
    for (int j = 0; j < 4; ++j) {
        int gnb = nBase + wn + j * 16 + lr * 4;
        float4 bv = *(const float4*)&bias[gnb];
        float mult = (gnb < 384) ? scale : 1.0f;   // q-section; group of 4 never straddles
#pragma unroll
        for (int i = 0; i < 4; ++i) {
            int gm = mBase + wm + i * 16 + lc;
            union { u16 h[4]; uint2 u; } pk;
            pk.h[0] = f2bf((acc[i][j][0] + bv.x) * mult);
            pk.h[1] = f2bf((acc[i][j][1] + bv.y) * mult);
            pk.h[2] = f2bf((acc[i][j][2] + bv.z) * mult);
            pk.h[3] = f2bf((acc[i][j][3] + bv.w) * mult);
            *(uint2*)(qkv_out + (size_t)gm * 1152 + gnb) = pk.u;
        }
    }
}

// ---------------- kernel 2: windowed attention (verified round-3 version) ----------
__global__ __launch_bounds__(256, 3) void attn_kernel(const u16* __restrict__ qkv,
                                                      const float* __restrict__ mask,
                                                      u16* __restrict__ aout) {
#define PST 68  // Vt LDS row stride (bf16 elems)
    __shared__ u16 Vt_s[4][32 * PST];
    const int tid = threadIdx.x;
    const int wave = tid >> 6, lane = tid & 63;
    const int lr = lane >> 4, lc = lane & 15;
    const int bid = blockIdx.x;
    const int b = bid / 3;
    const int h = (bid - b * 3) * 4 + wave;
    const int w = b & 63;
    const float* mrow = mask + (size_t)w * 2401;

    const u16* Q = qkv + (size_t)b * 49 * 1152 + h * 32;
    const u16* K = Q + 384;
    const u16* V = Q + 768;

    // stage V transposed: Vt[d][j], zero-padded j>=49
    {
        u16 vv[32];
        if (lane < 49) {
#pragma unroll
            for (int c = 0; c < 4; ++c)
                *(uint4*)&vv[c * 8] = *(const uint4*)(V + (size_t)lane * 1152 + c * 8);
        } else {
#pragma unroll
            for (int c = 0; c < 32; ++c) vv[c] = 0;
        }
#pragma unroll
        for (int d = 0; d < 32; ++d)
            Vt_s[wave][d * PST + lane] = vv[d];
    }

    // Q/K fragments straight from global (16B contiguous per lane, row stride 1152)
    short8 qf[4], kf[4];
    const short8 z8 = {0, 0, 0, 0, 0, 0, 0, 0};
#pragma unroll
    for (int i = 0; i < 4; ++i) {
        int row = i * 16 + lc;
        qf[i] = (row < 49) ? *(const short8*)(Q + (size_t)row * 1152 + lr * 8) : z8;
        kf[i] = (row < 49) ? *(const short8*)(K + (size_t)row * 1152 + lr * 8) : z8;
    }

    __syncthreads();   // Vt_s writes -> vfA reads

    // Vt A-frags for 16x16x16: lane (lr,lc) holds Vt[d=nt*16+lc][k=sj*16+lr*4 .. +3]
    s4v vfA[2][4];
#pragma unroll
    for (int nt = 0; nt < 2; ++nt)
#pragma unroll
        for (int sj = 0; sj < 4; ++sj)
            vfA[nt][sj] = *(const s4v*)&Vt_s[wave][(nt * 16 + lc) * PST + sj * 16 + lr * 4];

    // S2 = K Q^T (swapped): tile (si,sj): rows k (reg), cols q (lane)
    f32x4 S2[4][4] = {};
#pragma unroll
    for (int si = 0; si < 4; ++si)
#pragma unroll
        for (int sj = 0; sj < 4; ++sj)
            S2[si][sj] = __builtin_amdgcn_mfma_f32_16x16x32_bf16(kf[sj], qf[si], S2[si][sj], 0, 0, 0);

    // per-q-tile: softmax (in-register) -> P-frag pack -> PV -> store
    const size_t orow = (size_t)b * 49 * 384 + h * 32 + lr * 4;
#pragma unroll
    for (int si = 0; si < 4; ++si) {
        int q = si * 16 + lc;
        int im = (q < 49) ? q : 48;       // clamped; padded q never stored
        const float* mq = mrow + im * 49;
        float s = 0.0f;
        s4v pfq[4];
#pragma unroll
        for (int sj = 0; sj < 4; ++sj) {
            int kbase = sj * 16 + lr * 4;
            s4v pk;
#pragma unroll
            for (int r = 0; r < 4; ++r) {
                int k = kbase + r;
                float t = (k < 49) ? (S2[si][sj][r] + mq[k]) : -1e30f;
                float p = __expf(t);      // exp(-1e30) = 0: padded k contributes nothing
                s += p;
                pk[r] = (short)f2bf(p);
            }
            pfq[sj] = pk;
        }
        // complete k-sum: other k-chunks live on lanes differing in lr (bits 4,5)
        s += __shfl_xor(s, 16);
        s += __shfl_xor(s, 32);

        f32x4 O0 = {}, O1 = {};
#pragma unroll
        for (int sj = 0; sj < 4; ++sj) {
            O0 = MFMA16(vfA[0][sj], pfq[sj], O0);
            O1 = MFMA16(vfA[1][sj], pfq[sj], O1);
        }

        if (q < 49) {
            float rl = __builtin_amdgcn_rcpf(s);
            union { u16 h[4]; uint2 u; } pk;
            pk.h[0] = f2bf(O0[0] * rl); pk.h[1] = f2bf(O0[1] * rl);
            pk.h[2] = f2bf(O0[2] * rl); pk.h[3] = f2bf(O0[3] * rl);
            *(uint2*)(aout + orow + (size_t)q * 384) = pk.u;
            pk.h[0] = f2bf(O1[0] * rl); pk.h[1] = f2bf(O1[1] * rl);
            pk.h[2] = f2bf(O1[2] * rl); pk.h[3] = f2bf(O1[3] * rl);
            *(uint2*)(aout + orow + (size_t)q * 384 + 16) = pk.u;
        }
    }
#undef PST
}

// ---------------- kernel 3: proj GEMM (2-phase double-buffered prefetch) ----------------
__global__ __launch_bounds__(256) void proj_gemm(const u16* __restrict__ a,
                                                 const u16* __restrict__ wp,
                                                 const float* __restrict__ bias,
                                                 float* __restrict__ out) {
    __shared__ u16 As[2][128 * 32];
    __shared__ u16 Bs[2][128 * 32];
    const int tid = threadIdx.x;
    const int wave = tid >> 6, lane = tid & 63;
    const int lr = lane >> 4, lc = lane & 15;
    const int wm = (wave & 1) * 64, wn = (wave >> 1) * 64;
    const int lin = blockIdx.x;
    const int xcd = lin & 7;
    const int idx = lin >> 3;            // 0..293
    const int nBase = (idx % 3) * 128;
    const int mBase = (xcd * 98 + idx / 3) * 128;

    f32x4 acc[4][4] = {};

    const int srow = lane >> 2, scol = (lane & 3) * 8;
    const u16* aSrc = a  + (size_t)(mBase + wave * 32 + srow) * 384 + scol;
    const u16* bSrc = wp + (size_t)(nBase + wave * 32 + srow) * 384 + scol;

    auto stage = [&](int k0, int buf) {
        u16* aDst = &As[buf][wave * 1024];
        u16* bDst = &Bs[buf][wave * 1024];
        gld_lds16(aSrc + k0, aDst);
        gld_lds16(aSrc + k0 + (size_t)16 * 384, aDst + 512);
        gld_lds16(bSrc + k0, bDst);
        gld_lds16(bSrc + k0 + (size_t)16 * 384, bDst + 512);
    };
    auto compute = [&](int buf) {
        short8 af[4], bfr[4];
#pragma unroll
        for (int i = 0; i < 4; ++i)
            af[i] = *(const short8*)&As[buf][(wm + i * 16 + lc) * 32 + lr * 8];
#pragma unroll
        for (int j = 0; j < 4; ++j)
            bfr[j] = *(const short8*)&Bs[buf][(wn + j * 16 + lc) * 32 + lr * 8];
#pragma unroll
        for (int i = 0; i < 4; ++i)
#pragma unroll
            for (int j = 0; j < 4; ++j)
                acc[i][j] = __builtin_amdgcn_mfma_f32_16x16x32_bf16(bfr[j], af[i], acc[i][j], 0, 0, 0);
    };

    stage(0, 0);
    __syncthreads();
#pragma unroll
    for (int t = 0; t < 11; ++t) {
        stage((t + 1) * 32, (t + 1) & 1);
        compute(t & 1);
        __syncthreads();
    }
    compute(11 & 1);

    // epilogue: swapped-C mapping: m = wm+i*16+lc (lane), n = wn+j*16+lr*4+r (reg)
#pragma unroll
    for (int j = 0; j < 4; ++j) {
        int gnb = nBase + wn + j * 16 + lr * 4;
        float4 bv = *(const float4*)&bias[gnb];
#pragma unroll
        for (int i = 0; i < 4; ++i) {
            int gm = mBase + wm + i * 16 + lc;
            float4 o;
            o.x = acc[i][j][0] + bv.x;
            o.y = acc[i][j][1] + bv.y;
            o.z = acc[i][j][2] + bv.z;
            o.w = acc[i][j][3] + bv.w;
            *(float4*)(out + (size_t)gm * 384 + gnb) = o;
        }
    }
}

// ---------------- launch ----------------
extern "C" void kernel_launch(void* const* d_in, const int* in_sizes, int n_in,
                              void* d_out, int out_size, void* d_ws, size_t ws_size,
                              hipStream_t stream) {
    const float* x      = (const float*)d_in[0];
    const float* mask   = (const float*)d_in[1];
    const float* qkv_w  = (const float*)d_in[2];
    const float* qkv_b  = (const float*)d_in[3];
    const float* proj_w = (const float*)d_in[4];
    const float* proj_b = (const float*)d_in[5];
    float* out = (float*)d_out;

    char* ws = (char*)d_ws;
    u16* wq   = (u16*)ws;                                   // 1152*384*2   = 884736 B
    u16* wp   = (u16*)(ws + 884736);                        // 384*384*2    = 294912 B
    u16* qkvb = (u16*)(ws + 1179648);                       // 231211008 B
    // xb aliases the attn-out buffer: xb is dead before attn_kernel writes it
    u16* xb   = (u16*)(ws + 232390656);                     // 77070336 B
    u16* attn = xb;

    prep_all<<<19104, 256, 0, stream>>>(x, qkv_w, proj_w, xb, wq, wp);
    qkv_gemm<<<7056, 256, 0, stream>>>(xb, wq, qkv_b, qkvb);
    attn_kernel<<<6144, 256, 0, stream>>>(qkvb, mask, attn);
    proj_gemm<<<2352, 256, 0, stream>>>(attn, wp, proj_b, out);
}